// Round 3
// baseline (469.967 us; speedup 1.0000x reference)
//
#include <hip/hip_runtime.h>
#include <math.h>

#define NATOMS 20000
#define NEDGES 400000
#define EMBD   256
#define NRBF   50
#define NGATE  10
#define FOUT   128
#define APB    8       // atoms per block in k_main
#define OUTERC 5.0f

#define RBF_D    (5.0f/49.0f)
#define RBF_INVD (49.0f/5.0f)
#define RBF_C2   (-0.5f*(49.0f/5.0f)*(49.0f/5.0f)*1.4426950408889634f)
#define PI_OVER_OUTER 0.62831853071795864769f

static __device__ __forceinline__ float softplusf(float x){
    return (x > 15.0f) ? x : __logf(1.0f + __expf(x));
}
// round-to-nearest-even bf16, result in HIGH 16 bits
static __device__ __forceinline__ unsigned bfr(float v){
    unsigned u = __float_as_uint(v);
    return (u + 0x7fffu + ((u >> 16) & 1u)) & 0xffff0000u;
}
#define BLO(u) __uint_as_float((u) << 16)
#define BHI(u) __uint_as_float((u) & 0xffff0000u)

// ================= k_ag: gate/R/sv rows (blocks 0..51) + degree count (52..) ======
__global__ __launch_bounds__(256) void k_ag(
    const float* __restrict__ Wd, const float* __restrict__ Wdt,
    const float* __restrict__ bd, const float* __restrict__ bdt,
    const float* __restrict__ bgam, const float* __restrict__ Wgam,
    const float* __restrict__ Wexp, const float* __restrict__ bexp,
    const float* __restrict__ Wg, const float* __restrict__ Wn,
    const int* __restrict__ esrc, int* __restrict__ counts,
    float* __restrict__ R0, float* __restrict__ R1,
    float* __restrict__ Qg, float* __restrict__ Qn, float* __restrict__ sv)
{
    const int b = blockIdx.x, t = threadIdx.x;
    if (b >= 52) {
        int e = (b - 52) * 256 + t;
        if (e < NEDGES) atomicAdd(&counts[esrc[e]], 1);
        return;
    }
    __shared__ float ya[256], za[256];
    const int m = b;    // 0..51 rows of Y=[Wd@Wdt(50); bd@Wdt; bdt]
    float s;
    if (m < 50) {
        const float* wr = Wd + m*EMBD;
        s = 0.f;
        #pragma unroll 8
        for (int k = 0; k < EMBD; k++) s += wr[k] * Wdt[k*EMBD + t];
    } else if (m == 50) {
        s = 0.f;
        #pragma unroll 8
        for (int k = 0; k < EMBD; k++) s += bd[k] * Wdt[k*EMBD + t];
    } else {
        s = bdt[t];
    }
    ya[t] = s;
    __syncthreads();
    s = 0.f;
    #pragma unroll 8
    for (int k = 0; k < EMBD; k++) s += ya[k] * Wgam[k*EMBD + t];
    if (m == 51) s += bgam[t];
    za[t] = s;
    __syncthreads();
    const int half = t >> 7, ff = t & 127;
    const float* WX = Wexp + (size_t)half*EMBD*FOUT;
    s = 0.f;
    #pragma unroll 8
    for (int k = 0; k < EMBD; k++) s += za[k] * WX[k*FOUT + ff];
    if (m < 50)       (half ? R1 : R0)[m*FOUT + ff] = s;
    else if (m == 50) sv[half*FOUT + ff] = s;
    else              sv[256 + half*FOUT + ff] = s + bexp[half*FOUT + ff];
    if (t < 20) {
        const int tt = t % 10;
        const float* WT = (t < 10) ? Wg : Wn;
        float q = 0.f;
        #pragma unroll 8
        for (int k = 0; k < EMBD; k++) q += ya[k] * WT[k*NGATE + tt];
        if (m < 50) { float* Q = (t < 10) ? Qg : Qn; Q[m*12 + tt] = q; }
        else {
            int off = (m == 50) ? ((t < 10) ? 512 : 532) : ((t < 10) ? 522 : 542);
            sv[off + tt] = q;
            float* Q = (t < 10) ? Qg : Qn; Q[m*12 + tt] = 0.f;   // zero-pad rows 50,51
        }
    }
}

// ================= k_ct: exclusive scan (block 0) + Ti/Tj tables (blocks 1..200) ==
__global__ __launch_bounds__(256) void k_ct(
    const int* __restrict__ counts, int* __restrict__ cursors,
    const float* __restrict__ emb,
    const float* __restrict__ Wai, const float* __restrict__ bai,
    const float* __restrict__ Waj, const float* __restrict__ baj,
    const float* __restrict__ Wgam, const float* __restrict__ Wexp,
    float* __restrict__ Ti0, float* __restrict__ Ti1,
    float* __restrict__ Tj0, float* __restrict__ Tj1)
{
    const int b = blockIdx.x, t = threadIdx.x;
    if (b == 0) {
        __shared__ int part[256];
        const int CH = (NATOMS + 255) / 256;
        int base = t * CH, s = 0;
        for (int i = 0; i < CH; i++) { int idx = base + i; if (idx < NATOMS) s += counts[idx]; }
        part[t] = s;
        __syncthreads();
        for (int d = 1; d < 256; d <<= 1) {
            int v = (t >= d) ? part[t - d] : 0;
            __syncthreads();
            part[t] += v;
            __syncthreads();
        }
        int run = (t == 0) ? 0 : part[t - 1];
        for (int i = 0; i < CH; i++) {
            int idx = base + i;
            if (idx < NATOMS) { cursors[idx] = run; run += counts[idx]; }
        }
        return;
    }
    __shared__ float ya[256], za[256];
    const int side = (b >= 101);
    const int m = side ? b - 101 : b - 1;
    const float* er = emb + m*EMBD;
    const float* W1 = side ? Waj : Wai;
    const float* b1 = side ? baj : bai;
    float s = b1[t];
    #pragma unroll 8
    for (int k = 0; k < EMBD; k++) s += er[k] * W1[k*EMBD + t];
    ya[t] = s;
    __syncthreads();
    const float* G = Wgam + (size_t)(side ? 512 : 256) * EMBD;
    s = 0.f;
    #pragma unroll 8
    for (int k = 0; k < EMBD; k++) s += ya[k] * G[k*EMBD + t];
    za[t] = s;
    __syncthreads();
    const int half = t >> 7, ff = t & 127;
    const float* WX = Wexp + (size_t)half*EMBD*FOUT;
    s = 0.f;
    #pragma unroll 8
    for (int k = 0; k < EMBD; k++) s += za[k] * WX[k*FOUT + ff];
    float* dst = side ? (half ? Tj1 : Tj0) : (half ? Ti1 : Ti0);
    dst[m*FOUT + ff] = s;
}

// ================= k_edge: transform + FULL 64B record CSR scatter ==============
// rec[p] = 16 dwords: rr[0..11] fp32 | ab bf16x2 | gg bf16x2 | xy bf16x2 | ez<<16
// zdj[p] = zd | j0<<8
__global__ __launch_bounds__(256) void k_edge(
    const int* __restrict__ z, const int* __restrict__ esrc, const int* __restrict__ edst,
    const float* __restrict__ ew, const float* __restrict__ evec, const float* __restrict__ noise,
    const float* __restrict__ Qg, const float* __restrict__ Qn, const float* __restrict__ sv,
    int* __restrict__ cursors,
    float4* __restrict__ rec, unsigned* __restrict__ zdj)
{
    __shared__ float qgL[52*12], qnL[52*12];
    __shared__ float nbuf[256*11];
    __shared__ float vbuf[768];
    const int t = threadIdx.x;
    const int e0 = blockIdx.x * 256;

    for (int i = t; i < 52*12; i += 256) { qgL[i] = Qg[i]; qnL[i] = Qn[i]; }
    #pragma unroll
    for (int q = 0; q < 10; q++) {
        int idx = q*256 + t; long long g = (long long)e0*10 + idx;
        if (g < (long long)NEDGES*10) { int r_ = idx/10; nbuf[r_*11 + (idx - r_*10)] = noise[g]; }
    }
    #pragma unroll
    for (int q = 0; q < 3; q++) {
        int idx = q*256 + t; long long g = (long long)e0*3 + idx;
        if (g < (long long)NEDGES*3) vbuf[idx] = evec[g];
    }
    __syncthreads();

    int e = e0 + t;
    if (e >= NEDGES) return;
    float w = ew[e];
    float C = (w < OUTERC) ? 0.5f*(__cosf(w*PI_OVER_OUTER) + 1.0f) : 0.0f;
    int iw = (int)(w * RBF_INVD);
    int j0 = (iw - 4) & ~3;
    j0 = max(0, min(40, j0));
    float rW[12];
    #pragma unroll
    for (int k = 0; k < 12; k++) { float tt = w - (j0+k)*RBF_D; rW[k] = exp2f(RBF_C2*tt*tt); }
    float hg[NGATE], hn[NGATE];
    #pragma unroll
    for (int g2 = 0; g2 < NGATE; g2++) { hg[g2] = 0.f; hn[g2] = 0.f; }
    #pragma unroll
    for (int k = 0; k < 12; k++) {
        float rk = rW[k];
        const float* qg = &qgL[(j0+k)*12];
        const float* qn = &qnL[(j0+k)*12];
        float4 ga = *(const float4*)qg; float4 gb = *(const float4*)(qg+4);
        float2 gc = *(const float2*)(qg+8);
        float4 na = *(const float4*)qn; float4 nb = *(const float4*)(qn+4);
        float2 nc = *(const float2*)(qn+8);
        hg[0]=fmaf(rk,ga.x,hg[0]); hg[1]=fmaf(rk,ga.y,hg[1]); hg[2]=fmaf(rk,ga.z,hg[2]); hg[3]=fmaf(rk,ga.w,hg[3]);
        hg[4]=fmaf(rk,gb.x,hg[4]); hg[5]=fmaf(rk,gb.y,hg[5]); hg[6]=fmaf(rk,gb.z,hg[6]); hg[7]=fmaf(rk,gb.w,hg[7]);
        hg[8]=fmaf(rk,gc.x,hg[8]); hg[9]=fmaf(rk,gc.y,hg[9]);
        hn[0]=fmaf(rk,na.x,hn[0]); hn[1]=fmaf(rk,na.y,hn[1]); hn[2]=fmaf(rk,na.z,hn[2]); hn[3]=fmaf(rk,na.w,hn[3]);
        hn[4]=fmaf(rk,nb.x,hn[4]); hn[5]=fmaf(rk,nb.y,hn[5]); hn[6]=fmaf(rk,nb.z,hn[6]); hn[7]=fmaf(rk,nb.w,hn[7]);
        hn[8]=fmaf(rk,nc.x,hn[8]); hn[9]=fmaf(rk,nc.y,hn[9]);
    }
    float H[NGATE];
    #pragma unroll
    for (int g2 = 0; g2 < NGATE; g2++) {
        float gv = C*(hg[g2] + sv[512+g2]) + sv[522+g2];
        float nv = C*(hn[g2] + sv[532+g2]) + sv[542+g2];
        H[g2] = gv + nbuf[t*11 + g2] * softplusf(nv);
    }
    float m1 = -INFINITY, m2 = -INFINITY;
    #pragma unroll
    for (int g2 = 0; g2 < NGATE; g2++) {
        float v = H[g2];
        if (v > m1) { m2 = m1; m1 = v; } else if (v > m2) { m2 = v; }
    }
    float den = 0.f;
    #pragma unroll
    for (int g2 = 0; g2 < NGATE; g2++) den += (H[g2] >= m2) ? __expf(H[g2] - m1) : 0.f;
    float inv = 1.0f / den;
    float g0 = inv;
    float g1 = __expf(m2 - m1) * inv;

    float ex = vbuf[t*3+0], ey = vbuf[t*3+1], ez = vbuf[t*3+2];
    float rn = rsqrtf(ex*ex + ey*ey + ez*ez);
    ex *= rn; ey *= rn; ez *= rn;
    int zd = z[edst[e]];
    int p = atomicAdd(&cursors[esrc[e]], 1);

    float4* rp = rec + (size_t)p*4;
    rp[0] = make_float4(rW[0], rW[1], rW[2],  rW[3]);
    rp[1] = make_float4(rW[4], rW[5], rW[6],  rW[7]);
    rp[2] = make_float4(rW[8], rW[9], rW[10], rW[11]);
    rp[3] = make_float4(__uint_as_float((bfr(C*g0)>>16)|bfr(C*g1)),
                        __uint_as_float((bfr(g0)>>16)|bfr(g1)),
                        __uint_as_float((bfr(ex)>>16)|bfr(ey)),
                        __uint_as_float(bfr(ez)));
    zdj[p] = (unsigned)zd | ((unsigned)j0 << 8);
}

// ================= k_main: streamed 64B records, VMEM broadcast, no LDS staging ==
// R-table: 13 NAMED float4 regs (F0..F12). Round-2 learning: with plain
// __launch_bounds__(256,3) the scheduler still TARGETS 8-waves/EU occupancy
// (64-VGPR budget) and remats/sinks everything (VGPR_Count=52!). Pin the
// occupancy with amdgpu_waves_per_eu(3,3) -> budget 512/3 = 168 VGPRs, so the
// F-table (52) + record pipeline (64) + accs fit in registers.
#define DOT3(RA,RB,RC,X,Y,Z) { \
    float pA_ = RA.x*X.x; pA_=fmaf(RA.z,X.z,pA_); pA_=fmaf(RB.x,Y.x,pA_); \
    pA_=fmaf(RB.z,Y.z,pA_); pA_=fmaf(RC.x,Z.x,pA_); pA_=fmaf(RC.z,Z.z,pA_); \
    float pB_ = RA.y*X.y; pB_=fmaf(RA.w,X.w,pB_); pB_=fmaf(RB.y,Y.y,pB_); \
    pB_=fmaf(RB.w,Y.w,pB_); pB_=fmaf(RC.y,Z.y,pB_); pB_=fmaf(RC.w,Z.w,pB_); \
    acc = pA_ + pB_; }

#define FLUSH() { \
    accS[aCur-aBeg][pair][f] = make_float4(accA0+accA1, accX0+accX1, accY0+accY1, accZ0+accZ1); \
    accA0=accX0=accY0=accZ0=0.f; accA1=accX1=accY1=accZ1=0.f; aCur++; \
    if (aCur < aEnd) { nextEnd = neNxt; dtV = dV + tiNxt; \
        int an = aCur + 1; \
        if (an < aEnd) { neNxt = cursors[an]; tiNxt = TiT[z[an]*FOUT + f]; } \
    } else nextEnd = 0x7fffffff; }

#define COMPE(GI, ZJ, A, B, Cc, D, TJ, aA, aX, aY, aZ) { \
    int gi = (GI); \
    while (gi == nextEnd) FLUSH() \
    int sw = (__builtin_amdgcn_readfirstlane((int)(ZJ)) >> 10) & 0xf; \
    unsigned du = __float_as_uint(D.x), gu = __float_as_uint(D.y); \
    unsigned xu = __float_as_uint(D.z), eu = __float_as_uint(D.w); \
    float aa  = pair ? BHI(du) : BLO(du); \
    float gg_ = pair ? BHI(gu) : BLO(gu); \
    float acc; \
    switch (sw) { \
      case 0: DOT3(A,B,Cc,F0,F1,F2)    break; case 1: DOT3(A,B,Cc,F1,F2,F3)    break; \
      case 2: DOT3(A,B,Cc,F2,F3,F4)    break; case 3: DOT3(A,B,Cc,F3,F4,F5)    break; \
      case 4: DOT3(A,B,Cc,F4,F5,F6)    break; case 5: DOT3(A,B,Cc,F5,F6,F7)    break; \
      case 6: DOT3(A,B,Cc,F6,F7,F8)    break; case 7: DOT3(A,B,Cc,F7,F8,F9)    break; \
      case 8: DOT3(A,B,Cc,F8,F9,F10)   break; case 9: DOT3(A,B,Cc,F9,F10,F11)  break; \
      default: DOT3(A,B,Cc,F10,F11,F12) break; } \
    float part_ = fmaf(aa, acc + sV, gg_ * (dtV + (TJ))); \
    aA += part_; \
    aX = fmaf(BLO(xu), part_, aX); \
    aY = fmaf(BHI(xu), part_, aY); \
    aZ = fmaf(BHI(eu), part_, aZ); }

__global__ __launch_bounds__(256)
__attribute__((amdgpu_waves_per_eu(3, 3)))
void k_main(
    const int* __restrict__ z, const int* __restrict__ cursors,
    const float4* __restrict__ rec, const unsigned* __restrict__ zdj,
    const float* __restrict__ R0, const float* __restrict__ R1,
    const float* __restrict__ Ti0, const float* __restrict__ Ti1,
    const float* __restrict__ Tj0, const float* __restrict__ Tj1,
    const float* __restrict__ sv, float* __restrict__ out)
{
    __shared__ float4 accS[APB][2][FOUT];
    const int tid = threadIdx.x, pair = tid >> 7, f = tid & 127;

    const float* Rtab = pair ? R1 : R0;
#define LDR(j) Rtab[(j)*FOUT + f]
    float4 F0  = make_float4(LDR(0),  LDR(1),  LDR(2),  LDR(3));
    float4 F1  = make_float4(LDR(4),  LDR(5),  LDR(6),  LDR(7));
    float4 F2  = make_float4(LDR(8),  LDR(9),  LDR(10), LDR(11));
    float4 F3  = make_float4(LDR(12), LDR(13), LDR(14), LDR(15));
    float4 F4  = make_float4(LDR(16), LDR(17), LDR(18), LDR(19));
    float4 F5  = make_float4(LDR(20), LDR(21), LDR(22), LDR(23));
    float4 F6  = make_float4(LDR(24), LDR(25), LDR(26), LDR(27));
    float4 F7  = make_float4(LDR(28), LDR(29), LDR(30), LDR(31));
    float4 F8  = make_float4(LDR(32), LDR(33), LDR(34), LDR(35));
    float4 F9  = make_float4(LDR(36), LDR(37), LDR(38), LDR(39));
    float4 F10 = make_float4(LDR(40), LDR(41), LDR(42), LDR(43));
    float4 F11 = make_float4(LDR(44), LDR(45), LDR(46), LDR(47));
    float4 F12 = make_float4(LDR(48), LDR(49), 0.f, 0.f);
#undef LDR
    // Pin the 52 R values in VGPRs: opaque redefinition blocks load rematerialization.
#define KEEP4(v) asm volatile("" : "+v"(v.x), "+v"(v.y), "+v"(v.z), "+v"(v.w))
    KEEP4(F0);  KEEP4(F1);  KEEP4(F2);  KEEP4(F3);  KEEP4(F4);  KEEP4(F5);
    KEEP4(F6);  KEEP4(F7);  KEEP4(F8);  KEEP4(F9);  KEEP4(F10); KEEP4(F11);
    KEEP4(F12);
#undef KEEP4

    const float* TiT = pair ? Ti1 : Ti0;
    const float* TjT = pair ? Tj1 : Tj0;
    const float sV = sv[pair*FOUT + f];
    const float dV = sv[256 + pair*FOUT + f];

    const int aBeg = blockIdx.x * APB, aEnd = aBeg + APB;
    const int eBeg = aBeg ? cursors[aBeg-1] : 0;
    const int eEnd = cursors[aEnd-1];

    int aCur = aBeg;
    int nextEnd = cursors[aCur];
    float dtV = dV + TiT[z[aCur]*FOUT + f];
    int   neNxt = (aBeg+1 < aEnd) ? cursors[aBeg+1] : 0x7fffffff;
    float tiNxt = (aBeg+1 < aEnd) ? TiT[z[aBeg+1]*FOUT + f] : 0.f;
    float accA0=0.f, accX0=0.f, accY0=0.f, accZ0=0.f;
    float accA1=0.f, accX1=0.f, accY1=0.f, accZ1=0.f;

    // prime the pipeline (pad after NEDGES makes over-reads safe)
    unsigned czj0 = zdj[eBeg],   czj1 = zdj[eBeg+1];
    unsigned nzj0 = zdj[eBeg+2], nzj1 = zdj[eBeg+3];
    const float4* rp0 = rec + (size_t)eBeg*4;
    float4 cA0=rp0[0], cB0=rp0[1], cC0=rp0[2], cD0=rp0[3];
    float4 cA1=rp0[4], cB1=rp0[5], cC1=rp0[6], cD1=rp0[7];
    float ctj0 = TjT[(czj0 & 0xff)*FOUT + f];
    float ctj1 = TjT[(czj1 & 0xff)*FOUT + f];

    for (int i = eBeg; i < eEnd; i += 2) {
        // issue next-pair loads (records i+2, i+3; tj via zdj loaded 1 iter ago; zdj i+4,i+5)
        const float4* np = rec + (size_t)(i+2)*4;
        float4 nA0=np[0], nB0=np[1], nC0=np[2], nD0=np[3];
        float4 nA1=np[4], nB1=np[5], nC1=np[6], nD1=np[7];
        float ntj0 = TjT[(nzj0 & 0xff)*FOUT + f];
        float ntj1 = TjT[(nzj1 & 0xff)*FOUT + f];
        unsigned mzj0 = zdj[i+4], mzj1 = zdj[i+5];

        COMPE(i,   czj0, cA0, cB0, cC0, cD0, ctj0, accA0, accX0, accY0, accZ0)
        if (i + 1 < eEnd) { COMPE(i+1, czj1, cA1, cB1, cC1, cD1, ctj1, accA1, accX1, accY1, accZ1) }

        cA0=nA0; cB0=nB0; cC0=nC0; cD0=nD0;
        cA1=nA1; cB1=nB1; cC1=nC1; cD1=nD1;
        czj0=nzj0; czj1=nzj1; nzj0=mzj0; nzj1=mzj1;
        ctj0=ntj0; ctj1=ntj1;
    }
    while (aCur < aEnd) {
        accS[aCur-aBeg][pair][f] = make_float4(accA0+accA1, accX0+accX1, accY0+accY1, accZ0+accZ1);
        accA0=accX0=accY0=accZ0=0.f; accA1=accX1=accY1=accZ1=0.f; aCur++;
    }
    __syncthreads();
    if (tid < FOUT) {
        #pragma unroll
        for (int a2 = 0; a2 < APB; a2++) {
            float4 v0 = accS[a2][0][tid];
            float4 v1 = accS[a2][1][tid];
            int atom = aBeg + a2;
            out[(size_t)atom*FOUT + tid] = v0.x + v1.x;
            float* vb = out + (size_t)NATOMS*FOUT + (size_t)atom*3*FOUT;
            vb[tid]        = v0.y + v1.y;
            vb[FOUT+tid]   = v0.z + v1.z;
            vb[2*FOUT+tid] = v0.w + v1.w;
        }
    }
}

extern "C" void kernel_launch(void* const* d_in, const int* in_sizes, int n_in,
                              void* d_out, int out_size, void* d_ws, size_t ws_size,
                              hipStream_t stream)
{
    const int*   z    = (const int*)d_in[0];
    const int*   ei   = (const int*)d_in[3];
    const int*   esrc = ei;
    const int*   edst = ei + NEDGES;
    const float* ew   = (const float*)d_in[4];
    const float* evec = (const float*)d_in[5];
    const float* nz   = (const float*)d_in[6];
    const float* emb  = (const float*)d_in[7];
    const float* Wd   = (const float*)d_in[8];
    const float* bd   = (const float*)d_in[9];
    const float* Wdt  = (const float*)d_in[10];
    const float* bdt  = (const float*)d_in[11];
    const float* Wai  = (const float*)d_in[12];
    const float* bai  = (const float*)d_in[13];
    const float* Waj  = (const float*)d_in[14];
    const float* baj  = (const float*)d_in[15];
    const float* Wgam = (const float*)d_in[16];
    const float* bgam = (const float*)d_in[17];
    const float* Wg   = (const float*)d_in[18];
    const float* Wn   = (const float*)d_in[19];
    const float* Wexp = (const float*)d_in[20];
    const float* bexp = (const float*)d_in[21];
    float* out = (float*)d_out;

    char* w = (char*)d_ws;
    auto alloc = [&](size_t bytes) -> void* {
        void* p = (void*)w;
        w += (bytes + 255) & ~(size_t)255;
        return p;
    };
    int*   counts  = (int*)alloc(NATOMS * 4);
    int*   cursors = (int*)alloc(NATOMS * 4);
    float* R0  = (float*)alloc(NRBF*FOUT*4);
    float* R1  = (float*)alloc(NRBF*FOUT*4);
    float* Qg  = (float*)alloc(52*12*4);
    float* Qn  = (float*)alloc(52*12*4);
    float* Ti0 = (float*)alloc(100*FOUT*4);
    float* Ti1 = (float*)alloc(100*FOUT*4);
    float* Tj0 = (float*)alloc(100*FOUT*4);
    float* Tj1 = (float*)alloc(100*FOUT*4);
    float* sv  = (float*)alloc(552*4);
    float4*   rec = (float4*)alloc(((size_t)NEDGES + 8)*64);  // pad: prefetch over-reads <= +3
    unsigned* zdj = (unsigned*)alloc(((size_t)NEDGES + 8)*4); // pad: over-reads <= +5

    hipMemsetAsync(counts, 0, NATOMS*4, stream);

    {
        int grid = 52 + (NEDGES + 255) / 256;   // 1615
        k_ag<<<grid, 256, 0, stream>>>(Wd, Wdt, bd, bdt, bgam, Wgam, Wexp, bexp,
                                       Wg, Wn, esrc, counts, R0, R1, Qg, Qn, sv);
    }
    k_ct<<<201, 256, 0, stream>>>(counts, cursors, emb, Wai, bai, Waj, baj,
                                  Wgam, Wexp, Ti0, Ti1, Tj0, Tj1);
    {
        int grid = (NEDGES + 255) / 256;        // 1563
        k_edge<<<grid, 256, 0, stream>>>(z, esrc, edst, ew, evec, nz,
                                         Qg, Qn, sv, cursors, rec, zdj);
    }
    {
        int grid = NATOMS / APB;                // 2500
        k_main<<<grid, 256, 0, stream>>>(z, cursors, rec, zdj,
                                         R0, R1, Ti0, Ti1, Tj0, Tj1, sv, out);
    }
}

// Round 4
// 421.929 us; speedup vs baseline: 1.1139x; 1.1139x over previous
//
#include <hip/hip_runtime.h>
#include <math.h>

#define NATOMS 20000
#define NEDGES 400000
#define EMBD   256
#define NRBF   50
#define NGATE  10
#define FOUT   128
#define APB    4       // atoms per block in k_main
#define OUTERC 5.0f

#define RBF_D    (5.0f/49.0f)
#define RBF_INVD (49.0f/5.0f)
#define RBF_C2   (-0.5f*(49.0f/5.0f)*(49.0f/5.0f)*1.4426950408889634f)
#define PI_OVER_OUTER 0.62831853071795864769f

static __device__ __forceinline__ float softplusf(float x){
    return (x > 15.0f) ? x : __logf(1.0f + __expf(x));
}
// round-to-nearest-even bf16, result in HIGH 16 bits
static __device__ __forceinline__ unsigned bfr(float v){
    unsigned u = __float_as_uint(v);
    return (u + 0x7fffu + ((u >> 16) & 1u)) & 0xffff0000u;
}
#define BLO(u) __uint_as_float((u) << 16)
#define BHI(u) __uint_as_float((u) & 0xffff0000u)

// ================= k_ag: gate/R/sv rows (blocks 0..51) + degree count (52..) ======
__global__ __launch_bounds__(256) void k_ag(
    const float* __restrict__ Wd, const float* __restrict__ Wdt,
    const float* __restrict__ bd, const float* __restrict__ bdt,
    const float* __restrict__ bgam, const float* __restrict__ Wgam,
    const float* __restrict__ Wexp, const float* __restrict__ bexp,
    const float* __restrict__ Wg, const float* __restrict__ Wn,
    const int* __restrict__ esrc, int* __restrict__ counts,
    float* __restrict__ R0, float* __restrict__ R1,
    float* __restrict__ Qg, float* __restrict__ Qn, float* __restrict__ sv)
{
    const int b = blockIdx.x, t = threadIdx.x;
    if (b >= 52) {
        int e = (b - 52) * 256 + t;
        if (e < NEDGES) atomicAdd(&counts[esrc[e]], 1);
        return;
    }
    __shared__ float ya[256], za[256];
    const int m = b;    // 0..51 rows of Y=[Wd@Wdt(50); bd@Wdt; bdt]
    float s;
    if (m < 50) {
        const float* wr = Wd + m*EMBD;
        s = 0.f;
        #pragma unroll 8
        for (int k = 0; k < EMBD; k++) s += wr[k] * Wdt[k*EMBD + t];
    } else if (m == 50) {
        s = 0.f;
        #pragma unroll 8
        for (int k = 0; k < EMBD; k++) s += bd[k] * Wdt[k*EMBD + t];
    } else {
        s = bdt[t];
    }
    ya[t] = s;
    __syncthreads();
    s = 0.f;
    #pragma unroll 8
    for (int k = 0; k < EMBD; k++) s += ya[k] * Wgam[k*EMBD + t];
    if (m == 51) s += bgam[t];
    za[t] = s;
    __syncthreads();
    const int half = t >> 7, ff = t & 127;
    const float* WX = Wexp + (size_t)half*EMBD*FOUT;
    s = 0.f;
    #pragma unroll 8
    for (int k = 0; k < EMBD; k++) s += za[k] * WX[k*FOUT + ff];
    if (m < 50)       (half ? R1 : R0)[m*FOUT + ff] = s;
    else if (m == 50) sv[half*FOUT + ff] = s;
    else              sv[256 + half*FOUT + ff] = s + bexp[half*FOUT + ff];
    if (t < 20) {
        const int tt = t % 10;
        const float* WT = (t < 10) ? Wg : Wn;
        float q = 0.f;
        #pragma unroll 8
        for (int k = 0; k < EMBD; k++) q += ya[k] * WT[k*NGATE + tt];
        if (m < 50) { float* Q = (t < 10) ? Qg : Qn; Q[m*12 + tt] = q; }
        else {
            int off = (m == 50) ? ((t < 10) ? 512 : 532) : ((t < 10) ? 522 : 542);
            sv[off + tt] = q;
            float* Q = (t < 10) ? Qg : Qn; Q[m*12 + tt] = 0.f;   // zero-pad rows 50,51
        }
    }
}

// ================= k_ct: exclusive scan (block 0) + Ti/Tj tables (blocks 1..200) ==
__global__ __launch_bounds__(256) void k_ct(
    const int* __restrict__ counts, int* __restrict__ cursors,
    const float* __restrict__ emb,
    const float* __restrict__ Wai, const float* __restrict__ bai,
    const float* __restrict__ Waj, const float* __restrict__ baj,
    const float* __restrict__ Wgam, const float* __restrict__ Wexp,
    float* __restrict__ Ti0, float* __restrict__ Ti1,
    float* __restrict__ Tj0, float* __restrict__ Tj1)
{
    const int b = blockIdx.x, t = threadIdx.x;
    if (b == 0) {
        __shared__ int part[256];
        const int CH = (NATOMS + 255) / 256;
        int base = t * CH, s = 0;
        for (int i = 0; i < CH; i++) { int idx = base + i; if (idx < NATOMS) s += counts[idx]; }
        part[t] = s;
        __syncthreads();
        for (int d = 1; d < 256; d <<= 1) {
            int v = (t >= d) ? part[t - d] : 0;
            __syncthreads();
            part[t] += v;
            __syncthreads();
        }
        int run = (t == 0) ? 0 : part[t - 1];
        for (int i = 0; i < CH; i++) {
            int idx = base + i;
            if (idx < NATOMS) { cursors[idx] = run; run += counts[idx]; }
        }
        return;
    }
    __shared__ float ya[256], za[256];
    const int side = (b >= 101);
    const int m = side ? b - 101 : b - 1;
    const float* er = emb + m*EMBD;
    const float* W1 = side ? Waj : Wai;
    const float* b1 = side ? baj : bai;
    float s = b1[t];
    #pragma unroll 8
    for (int k = 0; k < EMBD; k++) s += er[k] * W1[k*EMBD + t];
    ya[t] = s;
    __syncthreads();
    const float* G = Wgam + (size_t)(side ? 512 : 256) * EMBD;
    s = 0.f;
    #pragma unroll 8
    for (int k = 0; k < EMBD; k++) s += ya[k] * G[k*EMBD + t];
    za[t] = s;
    __syncthreads();
    const int half = t >> 7, ff = t & 127;
    const float* WX = Wexp + (size_t)half*EMBD*FOUT;
    s = 0.f;
    #pragma unroll 8
    for (int k = 0; k < EMBD; k++) s += za[k] * WX[k*FOUT + ff];
    float* dst = side ? (half ? Tj1 : Tj0) : (half ? Ti1 : Ti0);
    dst[m*FOUT + ff] = s;
}

// ================= k_edge: transform + 16B record CSR scatter ===================
// rec[p] = float4: { w fp32 | g0,g1 bf16x2 | ex,ey bf16x2 | ez bf16 hi + zd lo16 }
// zdj[p] = zd  (separate small stream for 2-iter tj prefetch lead in k_main)
__global__ __launch_bounds__(256) void k_edge(
    const int* __restrict__ z, const int* __restrict__ esrc, const int* __restrict__ edst,
    const float* __restrict__ ew, const float* __restrict__ evec, const float* __restrict__ noise,
    const float* __restrict__ Qg, const float* __restrict__ Qn, const float* __restrict__ sv,
    int* __restrict__ cursors,
    float4* __restrict__ rec, unsigned* __restrict__ zdj)
{
    __shared__ float qgL[52*12], qnL[52*12];
    __shared__ float nbuf[256*11];
    __shared__ float vbuf[768];
    const int t = threadIdx.x;
    const int e0 = blockIdx.x * 256;

    for (int i = t; i < 52*12; i += 256) { qgL[i] = Qg[i]; qnL[i] = Qn[i]; }
    #pragma unroll
    for (int q = 0; q < 10; q++) {
        int idx = q*256 + t; long long g = (long long)e0*10 + idx;
        if (g < (long long)NEDGES*10) { int r_ = idx/10; nbuf[r_*11 + (idx - r_*10)] = noise[g]; }
    }
    #pragma unroll
    for (int q = 0; q < 3; q++) {
        int idx = q*256 + t; long long g = (long long)e0*3 + idx;
        if (g < (long long)NEDGES*3) vbuf[idx] = evec[g];
    }
    __syncthreads();

    int e = e0 + t;
    if (e >= NEDGES) return;
    float w = ew[e];
    float C = (w < OUTERC) ? 0.5f*(__cosf(w*PI_OVER_OUTER) + 1.0f) : 0.0f;
    int iw = (int)(w * RBF_INVD);
    int j0 = (iw - 4) & ~3;
    j0 = max(0, min(40, j0));
    float rW[12];
    #pragma unroll
    for (int k = 0; k < 12; k++) { float tt = w - (j0+k)*RBF_D; rW[k] = exp2f(RBF_C2*tt*tt); }
    float hg[NGATE], hn[NGATE];
    #pragma unroll
    for (int g2 = 0; g2 < NGATE; g2++) { hg[g2] = 0.f; hn[g2] = 0.f; }
    #pragma unroll
    for (int k = 0; k < 12; k++) {
        float rk = rW[k];
        const float* qg = &qgL[(j0+k)*12];
        const float* qn = &qnL[(j0+k)*12];
        float4 ga = *(const float4*)qg; float4 gb = *(const float4*)(qg+4);
        float2 gc = *(const float2*)(qg+8);
        float4 na = *(const float4*)qn; float4 nb = *(const float4*)(qn+4);
        float2 nc = *(const float2*)(qn+8);
        hg[0]=fmaf(rk,ga.x,hg[0]); hg[1]=fmaf(rk,ga.y,hg[1]); hg[2]=fmaf(rk,ga.z,hg[2]); hg[3]=fmaf(rk,ga.w,hg[3]);
        hg[4]=fmaf(rk,gb.x,hg[4]); hg[5]=fmaf(rk,gb.y,hg[5]); hg[6]=fmaf(rk,gb.z,hg[6]); hg[7]=fmaf(rk,gb.w,hg[7]);
        hg[8]=fmaf(rk,gc.x,hg[8]); hg[9]=fmaf(rk,gc.y,hg[9]);
        hn[0]=fmaf(rk,na.x,hn[0]); hn[1]=fmaf(rk,na.y,hn[1]); hn[2]=fmaf(rk,na.z,hn[2]); hn[3]=fmaf(rk,na.w,hn[3]);
        hn[4]=fmaf(rk,nb.x,hn[4]); hn[5]=fmaf(rk,nb.y,hn[5]); hn[6]=fmaf(rk,nb.z,hn[6]); hn[7]=fmaf(rk,nb.w,hn[7]);
        hn[8]=fmaf(rk,nc.x,hn[8]); hn[9]=fmaf(rk,nc.y,hn[9]);
    }
    float H[NGATE];
    #pragma unroll
    for (int g2 = 0; g2 < NGATE; g2++) {
        float gv = C*(hg[g2] + sv[512+g2]) + sv[522+g2];
        float nv = C*(hn[g2] + sv[532+g2]) + sv[542+g2];
        H[g2] = gv + nbuf[t*11 + g2] * softplusf(nv);
    }
    float m1 = -INFINITY, m2 = -INFINITY;
    #pragma unroll
    for (int g2 = 0; g2 < NGATE; g2++) {
        float v = H[g2];
        if (v > m1) { m2 = m1; m1 = v; } else if (v > m2) { m2 = v; }
    }
    float den = 0.f;
    #pragma unroll
    for (int g2 = 0; g2 < NGATE; g2++) den += (H[g2] >= m2) ? __expf(H[g2] - m1) : 0.f;
    float inv = 1.0f / den;
    float g0 = inv;
    float g1 = __expf(m2 - m1) * inv;

    float ex = vbuf[t*3+0], ey = vbuf[t*3+1], ez = vbuf[t*3+2];
    float rn = rsqrtf(ex*ex + ey*ey + ez*ez);
    ex *= rn; ey *= rn; ez *= rn;
    int zd = z[edst[e]];
    int p = atomicAdd(&cursors[esrc[e]], 1);

    rec[p] = make_float4(w,
        __uint_as_float((bfr(g0)>>16) | bfr(g1)),
        __uint_as_float((bfr(ex)>>16) | bfr(ey)),
        __uint_as_float(bfr(ez) | (unsigned)zd));
    zdj[p] = (unsigned)zd;
}

// ================= k_main v2: P-factorization ===================================
// Stream phase (per edge, all 256 threads):
//   f-role:   acc += g_h * Tj[zd][f]  (+ evn-weighted vec accs)     ~5 fma
//   slot-role (tid<208; slot = (j=tid%52, v=tid/52)):
//     P_h[v][j] += base_j(w) * u_v * g_h,  base = C*gauss_j (j<50) | C (j=50) | 1 (j=51)
// Per-atom FLUSH: slot threads dump P regs -> Plds[pair][j][a*4+v]; f accs -> accS.
// Dot phase (once per block, after one barrier):
//   D[a][v] = sum_j Plds[pair][j][a*4+v] * row_j[f],  row = R (j<50) | sV | dV+Ti[z_a]
// This moves the 52-wide R-dot from per-EDGE (400k) to per-ATOM-BATCH, killing the
// 4.9 GB/dispatch L2 reload traffic that bound rounds 0-3 (VGPR war is moot: the
// streaming loop needs no R-table at all).
#define FLUSH() { \
    int aIdx_ = aCur - aBeg; \
    accS[aIdx_][pair][f] = make_float4(accA, accX, accY, accZ); \
    accA=accX=accY=accZ=0.f; \
    if (isSlot) { Plds[0][sj][aIdx_*4+vv] = P0; Plds[1][sj][aIdx_*4+vv] = P1; P0 = P1 = 0.f; } \
    aCur++; \
    if (aCur < aEnd) { nextEnd = neNxt; int an_ = aCur + 1; if (an_ < aEnd) neNxt = cursors[an_]; } \
    else nextEnd = 0x7fffffff; }

#define COMPE(GI, D, TJ) { \
    int gi = (GI); \
    while (gi == nextEnd) FLUSH() \
    float w_ = D.x; \
    unsigned gu = __float_as_uint(D.y), xu = __float_as_uint(D.z), eu = __float_as_uint(D.w); \
    float g0f = BLO(gu), g1f = BHI(gu); \
    float exf = BLO(xu), eyf = BHI(xu), ezf = BHI(eu); \
    float u_ = (pair ? g1f : g0f) * (TJ); \
    accA += u_; \
    accX = fmaf(exf, u_, accX); \
    accY = fmaf(eyf, u_, accY); \
    accZ = fmaf(ezf, u_, accZ); \
    if (isSlot) { \
        float Cc_ = (w_ < OUTERC) ? 0.5f*(__cosf(w_*PI_OVER_OUTER) + 1.0f) : 0.0f; \
        float t_ = w_ - sjf; \
        float base_ = (sj < 50) ? Cc_*exp2f(RBF_C2*t_*t_) : ((sj == 50) ? Cc_ : 1.0f); \
        float uv_ = (vv == 0) ? 1.0f : ((vv == 1) ? exf : ((vv == 2) ? eyf : ezf)); \
        float m_ = base_ * uv_; \
        P0 = fmaf(m_, g0f, P0); \
        P1 = fmaf(m_, g1f, P1); } }

#define DOT16(PA,PB,PC,PD,R_) { \
    D00=fmaf(PA.x,R_,D00); D01=fmaf(PA.y,R_,D01); D02=fmaf(PA.z,R_,D02); D03=fmaf(PA.w,R_,D03); \
    D10=fmaf(PB.x,R_,D10); D11=fmaf(PB.y,R_,D11); D12=fmaf(PB.z,R_,D12); D13=fmaf(PB.w,R_,D13); \
    D20=fmaf(PC.x,R_,D20); D21=fmaf(PC.y,R_,D21); D22=fmaf(PC.z,R_,D22); D23=fmaf(PC.w,R_,D23); \
    D30=fmaf(PD.x,R_,D30); D31=fmaf(PD.y,R_,D31); D32=fmaf(PD.z,R_,D32); D33=fmaf(PD.w,R_,D33); }

__global__ __launch_bounds__(256) void k_main(
    const int* __restrict__ z, const int* __restrict__ cursors,
    const float4* __restrict__ rec, const unsigned* __restrict__ zdj,
    const float* __restrict__ R0, const float* __restrict__ R1,
    const float* __restrict__ Ti0, const float* __restrict__ Ti1,
    const float* __restrict__ Tj0, const float* __restrict__ Tj1,
    const float* __restrict__ sv, float* __restrict__ out)
{
    __shared__ __align__(16) float Plds[2][52][16];   // [pair][j][a*4+v]
    __shared__ float4 accS[APB][2][FOUT];
    const int tid = threadIdx.x, pair = tid >> 7, f = tid & 127;
    const float* TjT = pair ? Tj1 : Tj0;

    const int sj = tid % 52, vv = tid / 52;           // slot decomposition
    const bool isSlot = (vv < 4);                     // tid < 208
    const float sjf = sj * RBF_D;
    float P0 = 0.f, P1 = 0.f;
    float accA=0.f, accX=0.f, accY=0.f, accZ=0.f;

    const int aBeg = blockIdx.x * APB, aEnd = aBeg + APB;
    const int eBeg = aBeg ? cursors[aBeg-1] : 0;
    const int eEnd = cursors[aEnd-1];

    int aCur = aBeg;
    int nextEnd = cursors[aCur];
    int neNxt = (aBeg+1 < aEnd) ? cursors[aBeg+1] : 0x7fffffff;

    // prime the pipeline (pad after NEDGES makes over-reads safe)
    unsigned czj0 = zdj[eBeg],   czj1 = zdj[eBeg+1];
    unsigned nzj0 = zdj[eBeg+2], nzj1 = zdj[eBeg+3];
    float4 c0 = rec[eBeg], c1 = rec[eBeg+1];
    float ctj0 = TjT[(czj0 & 0xff)*FOUT + f];
    float ctj1 = TjT[(czj1 & 0xff)*FOUT + f];

    for (int i = eBeg; i < eEnd; i += 2) {
        float4 n0 = rec[i+2], n1 = rec[i+3];
        float ntj0 = TjT[(nzj0 & 0xff)*FOUT + f];
        float ntj1 = TjT[(nzj1 & 0xff)*FOUT + f];
        unsigned mzj0 = zdj[i+4], mzj1 = zdj[i+5];

        COMPE(i,   c0, ctj0)
        if (i + 1 < eEnd) { COMPE(i+1, c1, ctj1) }

        c0 = n0; c1 = n1;
        czj0 = nzj0; czj1 = nzj1; nzj0 = mzj0; nzj1 = mzj1;
        ctj0 = ntj0; ctj1 = ntj1;
    }
    while (aCur < aEnd) FLUSH();
    __syncthreads();

    // ---- dot phase: D[a][v] = sum_j P[pair][j][a][v] * row_j[f] ----
    {
        const float* Rtab = pair ? R1 : R0;
        const float* TiT  = pair ? Ti1 : Ti0;
        const float sVv = sv[pair*FOUT + f];
        const float dVv = sv[256 + pair*FOUT + f];
        float D00=0,D01=0,D02=0,D03=0, D10=0,D11=0,D12=0,D13=0;
        float D20=0,D21=0,D22=0,D23=0, D30=0,D31=0,D32=0,D33=0;
        const float* Pb = &Plds[pair][0][0];
        #pragma unroll 5
        for (int j = 0; j < 50; j++) {
            float r = Rtab[j*FOUT + f];
            const float4* pp = (const float4*)(Pb + j*16);
            float4 pa = pp[0], pb = pp[1], pc = pp[2], pd = pp[3];
            DOT16(pa, pb, pc, pd, r)
        }
        {   // j = 50: constant row sV, weight C*g
            const float4* pp = (const float4*)(Pb + 50*16);
            float4 pa = pp[0], pb = pp[1], pc = pp[2], pd = pp[3];
            DOT16(pa, pb, pc, pd, sVv)
        }
        {   // j = 51: per-atom row dV + Ti[z_a], weight g
            const float4* pp = (const float4*)(Pb + 51*16);
            float4 pa = pp[0], pb = pp[1], pc = pp[2], pd = pp[3];
            float r0 = dVv + TiT[z[aBeg+0]*FOUT + f];
            float r1 = dVv + TiT[z[aBeg+1]*FOUT + f];
            float r2 = dVv + TiT[z[aBeg+2]*FOUT + f];
            float r3 = dVv + TiT[z[aBeg+3]*FOUT + f];
            D00=fmaf(pa.x,r0,D00); D01=fmaf(pa.y,r0,D01); D02=fmaf(pa.z,r0,D02); D03=fmaf(pa.w,r0,D03);
            D10=fmaf(pb.x,r1,D10); D11=fmaf(pb.y,r1,D11); D12=fmaf(pb.z,r1,D12); D13=fmaf(pb.w,r1,D13);
            D20=fmaf(pc.x,r2,D20); D21=fmaf(pc.y,r2,D21); D22=fmaf(pc.z,r2,D22); D23=fmaf(pc.w,r2,D23);
            D30=fmaf(pd.x,r3,D30); D31=fmaf(pd.y,r3,D31); D32=fmaf(pd.z,r3,D32); D33=fmaf(pd.w,r3,D33);
        }
        float4 t;
        t = accS[0][pair][f]; t.x+=D00; t.y+=D01; t.z+=D02; t.w+=D03; accS[0][pair][f] = t;
        t = accS[1][pair][f]; t.x+=D10; t.y+=D11; t.z+=D12; t.w+=D13; accS[1][pair][f] = t;
        t = accS[2][pair][f]; t.x+=D20; t.y+=D21; t.z+=D22; t.w+=D23; accS[2][pair][f] = t;
        t = accS[3][pair][f]; t.x+=D30; t.y+=D31; t.z+=D32; t.w+=D33; accS[3][pair][f] = t;
    }
    __syncthreads();
    if (tid < FOUT) {
        #pragma unroll
        for (int a2 = 0; a2 < APB; a2++) {
            float4 v0 = accS[a2][0][tid];
            float4 v1 = accS[a2][1][tid];
            int atom = aBeg + a2;
            out[(size_t)atom*FOUT + tid] = v0.x + v1.x;
            float* vb = out + (size_t)NATOMS*FOUT + (size_t)atom*3*FOUT;
            vb[tid]        = v0.y + v1.y;
            vb[FOUT+tid]   = v0.z + v1.z;
            vb[2*FOUT+tid] = v0.w + v1.w;
        }
    }
}

extern "C" void kernel_launch(void* const* d_in, const int* in_sizes, int n_in,
                              void* d_out, int out_size, void* d_ws, size_t ws_size,
                              hipStream_t stream)
{
    const int*   z    = (const int*)d_in[0];
    const int*   ei   = (const int*)d_in[3];
    const int*   esrc = ei;
    const int*   edst = ei + NEDGES;
    const float* ew   = (const float*)d_in[4];
    const float* evec = (const float*)d_in[5];
    const float* nz   = (const float*)d_in[6];
    const float* emb  = (const float*)d_in[7];
    const float* Wd   = (const float*)d_in[8];
    const float* bd   = (const float*)d_in[9];
    const float* Wdt  = (const float*)d_in[10];
    const float* bdt  = (const float*)d_in[11];
    const float* Wai  = (const float*)d_in[12];
    const float* bai  = (const float*)d_in[13];
    const float* Waj  = (const float*)d_in[14];
    const float* baj  = (const float*)d_in[15];
    const float* Wgam = (const float*)d_in[16];
    const float* bgam = (const float*)d_in[17];
    const float* Wg   = (const float*)d_in[18];
    const float* Wn   = (const float*)d_in[19];
    const float* Wexp = (const float*)d_in[20];
    const float* bexp = (const float*)d_in[21];
    float* out = (float*)d_out;

    char* w = (char*)d_ws;
    auto alloc = [&](size_t bytes) -> void* {
        void* p = (void*)w;
        w += (bytes + 255) & ~(size_t)255;
        return p;
    };
    int*   counts  = (int*)alloc(NATOMS * 4);
    int*   cursors = (int*)alloc(NATOMS * 4);
    float* R0  = (float*)alloc(NRBF*FOUT*4);
    float* R1  = (float*)alloc(NRBF*FOUT*4);
    float* Qg  = (float*)alloc(52*12*4);
    float* Qn  = (float*)alloc(52*12*4);
    float* Ti0 = (float*)alloc(100*FOUT*4);
    float* Ti1 = (float*)alloc(100*FOUT*4);
    float* Tj0 = (float*)alloc(100*FOUT*4);
    float* Tj1 = (float*)alloc(100*FOUT*4);
    float* sv  = (float*)alloc(552*4);
    float4*   rec = (float4*)alloc(((size_t)NEDGES + 8)*16);  // 16B records + prefetch pad
    unsigned* zdj = (unsigned*)alloc(((size_t)NEDGES + 8)*4); // pad: over-reads <= +5

    hipMemsetAsync(counts, 0, NATOMS*4, stream);

    {
        int grid = 52 + (NEDGES + 255) / 256;   // 1615
        k_ag<<<grid, 256, 0, stream>>>(Wd, Wdt, bd, bdt, bgam, Wgam, Wexp, bexp,
                                       Wg, Wn, esrc, counts, R0, R1, Qg, Qn, sv);
    }
    k_ct<<<201, 256, 0, stream>>>(counts, cursors, emb, Wai, bai, Waj, baj,
                                  Wgam, Wexp, Ti0, Ti1, Tj0, Tj1);
    {
        int grid = (NEDGES + 255) / 256;        // 1563
        k_edge<<<grid, 256, 0, stream>>>(z, esrc, edst, ew, evec, nz,
                                         Qg, Qn, sv, cursors, rec, zdj);
    }
    {
        int grid = NATOMS / APB;                // 5000
        k_main<<<grid, 256, 0, stream>>>(z, cursors, rec, zdj,
                                         R0, R1, Ti0, Ti1, Tj0, Tj1, sv, out);
    }
}